// Round 8
// baseline (418.059 us; speedup 1.0000x reference)
//
#include <hip/hip_runtime.h>
#include <hip/hip_bf16.h>

#define T_TOK 1024
#define H_DIM 1024
#define F_DIM 768
#define E_NUM 16
#define TOPK  4

#define BM 64
#define BN 64
#define BK 32
#define LDSS 40   // LDS row stride in ushorts (80B) -> <=2-way bank conflict (free)

typedef __attribute__((ext_vector_type(8))) short bf16x8;
typedef __attribute__((ext_vector_type(4))) float f32x4;
typedef unsigned short ushort_t;

__device__ __forceinline__ ushort_t f2bf(float f) {
  __hip_bfloat16 h = __float2bfloat16(f);
  return *reinterpret_cast<ushort_t*>(&h);
}

// ---------------- K0: zero output + counters ----------------
__global__ void k_zero(float* __restrict__ out, int n, int* __restrict__ cnt) {
  int i = blockIdx.x * blockDim.x + threadIdx.x;
  if (i < E_NUM) cnt[i] = 0;
  for (; i < n; i += gridDim.x * blockDim.x) out[i] = 0.f;
}

// ---------------- K1: router (1 wave per token) ----------------
__global__ __launch_bounds__(64) void k_router(
    const float* __restrict__ x, const float* __restrict__ gw,
    int* __restrict__ cnt, int* __restrict__ topk_id, float* __restrict__ topk_w) {
  int t = blockIdx.x;
  int lane = threadIdx.x;
  const float* xr = x + (size_t)t * H_DIM;

  float xv[16];
#pragma unroll
  for (int j = 0; j < 16; ++j) xv[j] = xr[lane + j * 64];

  float lg[E_NUM];
#pragma unroll
  for (int e = 0; e < E_NUM; ++e) {
    const float* g = gw + (size_t)e * H_DIM;
    float s = 0.f;
#pragma unroll
    for (int j = 0; j < 16; ++j) s += xv[j] * g[lane + j * 64];
#pragma unroll
    for (int off = 32; off >= 1; off >>= 1) s += __shfl_xor(s, off);
    lg[e] = s;
  }

  // top-4, first-index-on-ties (matches jax.lax.top_k)
  int ids[TOPK];
  float vals[TOPK];
  unsigned used = 0;
#pragma unroll
  for (int k = 0; k < TOPK; ++k) {
    float best = -3.0e38f;
    int bi = 0;
#pragma unroll
    for (int e = 0; e < E_NUM; ++e) {
      bool skip = (used >> e) & 1;
      if (!skip && lg[e] > best) { best = lg[e]; bi = e; }
    }
    used |= 1u << bi;
    ids[k] = bi;
    vals[k] = best;
  }
  float m = vals[0];
  float w[TOPK];
  float sum = 0.f;
#pragma unroll
  for (int k = 0; k < TOPK; ++k) { w[k] = __expf(vals[k] - m); sum += w[k]; }
  float inv = 1.f / sum;

  if (lane == 0) {
#pragma unroll
    for (int k = 0; k < TOPK; ++k) {
      topk_id[t * TOPK + k] = ids[k];
      topk_w[t * TOPK + k] = w[k] * inv;
      atomicAdd(&cnt[ids[k]], 1);
    }
  }
}

// ---------------- K2: exclusive scan of counts ----------------
__global__ void k_scan(const int* __restrict__ cnt, int* __restrict__ offs,
                       int* __restrict__ cursor) {
  if (threadIdx.x == 0) {
    int r = 0;
    for (int e = 0; e < E_NUM; ++e) { offs[e] = r; r += cnt[e]; cursor[e] = 0; }
  }
}

// ---------------- K3: fill per-expert slot lists ----------------
__global__ void k_assign(const int* __restrict__ topk_id, const float* __restrict__ topk_w,
                         const int* __restrict__ offs, int* __restrict__ cursor,
                         int* __restrict__ slot_tok, float* __restrict__ slot_w) {
  int i = blockIdx.x * blockDim.x + threadIdx.x;
  if (i >= T_TOK * TOPK) return;
  int e = topk_id[i];
  int pos = offs[e] + atomicAdd(&cursor[e], 1);
  slot_tok[pos] = i >> 2;
  slot_w[pos] = topk_w[i];
}

// ---------------- K4: GEMM1  act = silu(x@w1g^T) * (x@w1u^T)  ----------------
__global__ __launch_bounds__(256) void k_gemm1(
    const float* __restrict__ x, const float* __restrict__ w1,
    const int* __restrict__ slot_tok, const int* __restrict__ offs,
    const int* __restrict__ cnt, __hip_bfloat16* __restrict__ act) {
  int e = blockIdx.z;
  int m0 = blockIdx.y * BM;
  int cntE = cnt[e];
  if (m0 >= cntE) return;
  int n0 = blockIdx.x * BN;
  int off = offs[e];

  __shared__ ushort_t sA[BM * LDSS];
  __shared__ ushort_t sG[BN * LDSS];
  __shared__ ushort_t sU[BN * LDSS];
  __shared__ int tok_s[BM];

  int tid = threadIdx.x;
  if (tid < BM) {
    int r = m0 + tid;
    tok_s[tid] = (r < cntE) ? slot_tok[off + r] : -1;
  }
  __syncthreads();

  int srow = tid >> 2;          // 0..63 staging row
  int scol = (tid & 3) * 8;     // 0,8,16,24 (f32/bf16 elements)
  int mytok = tok_s[srow];
  const float* aptr = x + (size_t)(mytok < 0 ? 0 : mytok) * H_DIM + scol;
  const float* gptr = w1 + ((size_t)e * 2 * F_DIM + n0 + srow) * H_DIM + scol;
  const float* uptr = gptr + (size_t)F_DIM * H_DIM;

  int wave = tid >> 6;
  int lane = tid & 63;
  int wr = wave >> 1, wc = wave & 1;
  int lrow = lane & 15;
  int kgrp = lane >> 4;

  f32x4 accg[2][2] = {};
  f32x4 accu[2][2] = {};

  int aoff0 = (wr * 32 + lrow) * LDSS + kgrp * 8;
  int boff0 = (wc * 32 + lrow) * LDSS + kgrp * 8;

  for (int k0 = 0; k0 < H_DIM; k0 += BK) {
    float4 va0 = make_float4(0, 0, 0, 0), va1 = va0;
    if (mytok >= 0) {
      va0 = *(const float4*)(aptr + k0);
      va1 = *(const float4*)(aptr + k0 + 4);
    }
    float4 vg0 = *(const float4*)(gptr + k0);
    float4 vg1 = *(const float4*)(gptr + k0 + 4);
    float4 vu0 = *(const float4*)(uptr + k0);
    float4 vu1 = *(const float4*)(uptr + k0 + 4);

    __syncthreads();  // previous iter's compute done before overwrite
    {
      bf16x8 v;
      v[0] = (short)f2bf(va0.x); v[1] = (short)f2bf(va0.y); v[2] = (short)f2bf(va0.z); v[3] = (short)f2bf(va0.w);
      v[4] = (short)f2bf(va1.x); v[5] = (short)f2bf(va1.y); v[6] = (short)f2bf(va1.z); v[7] = (short)f2bf(va1.w);
      *(bf16x8*)&sA[srow * LDSS + scol] = v;
      v[0] = (short)f2bf(vg0.x); v[1] = (short)f2bf(vg0.y); v[2] = (short)f2bf(vg0.z); v[3] = (short)f2bf(vg0.w);
      v[4] = (short)f2bf(vg1.x); v[5] = (short)f2bf(vg1.y); v[6] = (short)f2bf(vg1.z); v[7] = (short)f2bf(vg1.w);
      *(bf16x8*)&sG[srow * LDSS + scol] = v;
      v[0] = (short)f2bf(vu0.x); v[1] = (short)f2bf(vu0.y); v[2] = (short)f2bf(vu0.z); v[3] = (short)f2bf(vu0.w);
      v[4] = (short)f2bf(vu1.x); v[5] = (short)f2bf(vu1.y); v[6] = (short)f2bf(vu1.z); v[7] = (short)f2bf(vu1.w);
      *(bf16x8*)&sU[srow * LDSS + scol] = v;
    }
    __syncthreads();

    bf16x8 af[2], gf[2], uf[2];
    af[0] = *(const bf16x8*)&sA[aoff0];
    af[1] = *(const bf16x8*)&sA[aoff0 + 16 * LDSS];
    gf[0] = *(const bf16x8*)&sG[boff0];
    gf[1] = *(const bf16x8*)&sG[boff0 + 16 * LDSS];
    uf[0] = *(const bf16x8*)&sU[boff0];
    uf[1] = *(const bf16x8*)&sU[boff0 + 16 * LDSS];
#pragma unroll
    for (int i = 0; i < 2; ++i)
#pragma unroll
      for (int j = 0; j < 2; ++j) {
        accg[i][j] = __builtin_amdgcn_mfma_f32_16x16x32_bf16(af[i], gf[j], accg[i][j], 0, 0, 0);
        accu[i][j] = __builtin_amdgcn_mfma_f32_16x16x32_bf16(af[i], uf[j], accu[i][j], 0, 0, 0);
      }
  }

  // epilogue: silu(g)*u -> act (bf16). C layout: col=lane&15, row=(lane>>4)*4+reg
#pragma unroll
  for (int i = 0; i < 2; ++i) {
#pragma unroll
    for (int r = 0; r < 4; ++r) {
      int row = wr * 32 + i * 16 + kgrp * 4 + r;
      if (m0 + row < cntE) {
        size_t gslot = (size_t)(off + m0 + row);
        __hip_bfloat16* ap = act + gslot * F_DIM + n0 + wc * 32 + lrow;
#pragma unroll
        for (int j = 0; j < 2; ++j) {
          float g = accg[i][j][r];
          float u = accu[i][j][r];
          float a = (g / (1.f + __expf(-g))) * u;
          ap[j * 16] = __float2bfloat16(a);
        }
      }
    }
  }
}

// ---------------- K5: GEMM2  out[t] += w_slot * (act @ w2^T) ----------------
__global__ __launch_bounds__(256) void k_gemm2(
    const __hip_bfloat16* __restrict__ act, const float* __restrict__ w2,
    const int* __restrict__ slot_tok, const float* __restrict__ slot_w,
    const int* __restrict__ offs, const int* __restrict__ cnt,
    float* __restrict__ out) {
  int e = blockIdx.z;
  int m0 = blockIdx.y * BM;
  int cntE = cnt[e];
  if (m0 >= cntE) return;
  int n0 = blockIdx.x * BN;
  int off = offs[e];

  __shared__ ushort_t sA[BM * LDSS];
  __shared__ ushort_t sB[BN * LDSS];
  __shared__ int tok_s[BM];
  __shared__ float w_s[BM];

  int tid = threadIdx.x;
  if (tid < BM) {
    int r = m0 + tid;
    tok_s[tid] = (r < cntE) ? slot_tok[off + r] : 0;
    w_s[tid] = (r < cntE) ? slot_w[off + r] : 0.f;
  }
  __syncthreads();

  int srow = tid >> 2;
  int scol = (tid & 3) * 8;
  bool arow_ok = (m0 + srow) < cntE;
  const ushort_t* aptr = (const ushort_t*)act + (size_t)(off + m0 + (arow_ok ? srow : 0)) * F_DIM + scol;
  const float* bptr = w2 + ((size_t)e * H_DIM + n0 + srow) * F_DIM + scol;

  int wave = tid >> 6;
  int lane = tid & 63;
  int wr = wave >> 1, wc = wave & 1;
  int lrow = lane & 15;
  int kgrp = lane >> 4;

  f32x4 acc[2][2] = {};

  int aoff0 = (wr * 32 + lrow) * LDSS + kgrp * 8;
  int boff0 = (wc * 32 + lrow) * LDSS + kgrp * 8;

  for (int k0 = 0; k0 < F_DIM; k0 += BK) {
    bf16x8 av = {0, 0, 0, 0, 0, 0, 0, 0};
    if (arow_ok) av = *(const bf16x8*)(aptr + k0);
    float4 vb0 = *(const float4*)(bptr + k0);
    float4 vb1 = *(const float4*)(bptr + k0 + 4);

    __syncthreads();
    *(bf16x8*)&sA[srow * LDSS + scol] = av;
    {
      bf16x8 v;
      v[0] = (short)f2bf(vb0.x); v[1] = (short)f2bf(vb0.y); v[2] = (short)f2bf(vb0.z); v[3] = (short)f2bf(vb0.w);
      v[4] = (short)f2bf(vb1.x); v[5] = (short)f2bf(vb1.y); v[6] = (short)f2bf(vb1.z); v[7] = (short)f2bf(vb1.w);
      *(bf16x8*)&sB[srow * LDSS + scol] = v;
    }
    __syncthreads();

    bf16x8 af[2], bf[2];
    af[0] = *(const bf16x8*)&sA[aoff0];
    af[1] = *(const bf16x8*)&sA[aoff0 + 16 * LDSS];
    bf[0] = *(const bf16x8*)&sB[boff0];
    bf[1] = *(const bf16x8*)&sB[boff0 + 16 * LDSS];
#pragma unroll
    for (int i = 0; i < 2; ++i)
#pragma unroll
      for (int j = 0; j < 2; ++j)
        acc[i][j] = __builtin_amdgcn_mfma_f32_16x16x32_bf16(af[i], bf[j], acc[i][j], 0, 0, 0);
  }

#pragma unroll
  for (int i = 0; i < 2; ++i) {
#pragma unroll
    for (int r = 0; r < 4; ++r) {
      int row = wr * 32 + i * 16 + kgrp * 4 + r;
      if (m0 + row < cntE) {
        int tok = tok_s[row];
        float wgt = w_s[row];
        float* op = out + (size_t)tok * H_DIM + n0 + wc * 32 + lrow;
#pragma unroll
        for (int j = 0; j < 2; ++j)
          atomicAdd(op + j * 16, acc[i][j][r] * wgt);
      }
    }
  }
}

// ---------------- launch ----------------
extern "C" void kernel_launch(void* const* d_in, const int* in_sizes, int n_in,
                              void* d_out, int out_size, void* d_ws, size_t ws_size,
                              hipStream_t stream) {
  const float* x  = (const float*)d_in[0];
  const float* gw = (const float*)d_in[1];
  const float* w1 = (const float*)d_in[2];
  const float* w2 = (const float*)d_in[3];
  float* out = (float*)d_out;

  char* base = (char*)d_ws;
  int* cnt      = (int*)(base);
  int* cursor   = (int*)(base + 64);
  int* offs     = (int*)(base + 128);
  int* topk_id  = (int*)(base + 256);
  float* topk_w = (float*)(base + 256 + 16384);
  int* slot_tok = (int*)(base + 256 + 32768);
  float* slot_w = (float*)(base + 256 + 49152);
  __hip_bfloat16* act = (__hip_bfloat16*)(base + 256 + 65536);  // 4096*768 bf16 = 6.29MB

  k_zero<<<512, 256, 0, stream>>>(out, T_TOK * H_DIM, cnt);
  k_router<<<T_TOK, 64, 0, stream>>>(x, gw, cnt, topk_id, topk_w);
  k_scan<<<1, 64, 0, stream>>>(cnt, offs, cursor);
  k_assign<<<(T_TOK * TOPK + 255) / 256, 256, 0, stream>>>(topk_id, topk_w, offs, cursor, slot_tok, slot_w);
  k_gemm1<<<dim3(F_DIM / BN, T_TOK / BM, E_NUM), 256, 0, stream>>>(x, w1, slot_tok, offs, cnt, act);
  k_gemm2<<<dim3(H_DIM / BN, T_TOK / BM, E_NUM), 256, 0, stream>>>(act, w2, slot_tok, slot_w, offs, cnt, out);
}

// Round 13
// 316.204 us; speedup vs baseline: 1.3221x; 1.3221x over previous
//
#include <hip/hip_runtime.h>
#include <hip/hip_bf16.h>

#define T_TOK 1024
#define H_DIM 1024
#define F_DIM 768
#define E_NUM 16
#define TOPK  4

#define BM 64
#define BN 64
#define BK 32
#define LDSS 40   // LDS row stride in ushorts (80B) -> <=2-way bank conflict (free)

typedef __attribute__((ext_vector_type(8))) short bf16x8;
typedef __attribute__((ext_vector_type(4))) float f32x4;
typedef unsigned short ushort_t;

__device__ __forceinline__ ushort_t f2bf(float f) {
  __hip_bfloat16 h = __float2bfloat16(f);
  return *reinterpret_cast<ushort_t*>(&h);
}

// ---------------- K0: zero output + counters ----------------
__global__ void k_zero(float* __restrict__ out, int n, int* __restrict__ cnt) {
  int i = blockIdx.x * blockDim.x + threadIdx.x;
  if (i < E_NUM) cnt[i] = 0;
  for (; i < n; i += gridDim.x * blockDim.x) out[i] = 0.f;
}

// ---------------- K0b: f32 -> bf16 bulk convert (8 elem/thread/iter) --------
__global__ __launch_bounds__(256) void k_cvt(const float* __restrict__ src,
                                             ushort_t* __restrict__ dst, int n8) {
  int i = blockIdx.x * blockDim.x + threadIdx.x;
  int stride = gridDim.x * blockDim.x;
  for (; i < n8; i += stride) {
    const float4* s = (const float4*)(src + (size_t)i * 8);
    float4 a = s[0], b = s[1];
    bf16x8 v;
    v[0] = (short)f2bf(a.x); v[1] = (short)f2bf(a.y); v[2] = (short)f2bf(a.z); v[3] = (short)f2bf(a.w);
    v[4] = (short)f2bf(b.x); v[5] = (short)f2bf(b.y); v[6] = (short)f2bf(b.z); v[7] = (short)f2bf(b.w);
    *(bf16x8*)(dst + (size_t)i * 8) = v;
  }
}

// ---------------- K1a: logits — one wave per (token, expert) ----------------
__global__ __launch_bounds__(256) void k_logits(
    const float* __restrict__ x, const float* __restrict__ gw,
    float* __restrict__ logits) {
  int wid = blockIdx.x * 4 + (threadIdx.x >> 6);   // 0..16383
  int lane = threadIdx.x & 63;
  int t = wid >> 4;
  int e = wid & (E_NUM - 1);
  const float* xr = x + (size_t)t * H_DIM;
  const float* g  = gw + (size_t)e * H_DIM;
  float s = 0.f;
#pragma unroll
  for (int j = 0; j < 16; ++j) s += xr[lane + j * 64] * g[lane + j * 64];
#pragma unroll
  for (int off = 32; off >= 1; off >>= 1) s += __shfl_xor(s, off);
  if (lane == 0) logits[t * E_NUM + e] = s;
}

// ---------------- K1b: top-4 + softmax — one thread per token ----------------
__global__ __launch_bounds__(256) void k_topk(
    const float* __restrict__ logits, int* __restrict__ cnt,
    int* __restrict__ topk_id, float* __restrict__ topk_w) {
  int t = blockIdx.x * blockDim.x + threadIdx.x;
  if (t >= T_TOK) return;

  float lg[E_NUM];
#pragma unroll
  for (int e = 0; e < E_NUM; ++e) lg[e] = logits[t * E_NUM + e];

  int ids[TOPK];
  float vals[TOPK];
  unsigned used = 0;
#pragma unroll
  for (int k = 0; k < TOPK; ++k) {
    float best = -3.0e38f;
    int bi = 0;
#pragma unroll
    for (int e = 0; e < E_NUM; ++e) {
      bool skip = (used >> e) & 1;
      if (!skip && lg[e] > best) { best = lg[e]; bi = e; }
    }
    used |= 1u << bi;
    ids[k] = bi;
    vals[k] = best;
  }
  float m = vals[0];
  float w[TOPK];
  float sum = 0.f;
#pragma unroll
  for (int k = 0; k < TOPK; ++k) { w[k] = __expf(vals[k] - m); sum += w[k]; }
  float inv = 1.f / sum;

#pragma unroll
  for (int k = 0; k < TOPK; ++k) {
    topk_id[t * TOPK + k] = ids[k];
    topk_w[t * TOPK + k] = w[k] * inv;
    atomicAdd(&cnt[ids[k]], 1);
  }
}

// ---------------- K2: exclusive scan of counts ----------------
__global__ void k_scan(const int* __restrict__ cnt, int* __restrict__ offs,
                       int* __restrict__ cursor) {
  if (threadIdx.x == 0) {
    int r = 0;
    for (int e = 0; e < E_NUM; ++e) { offs[e] = r; r += cnt[e]; cursor[e] = 0; }
  }
}

// ---------------- K3: fill per-expert slot lists ----------------
__global__ void k_assign(const int* __restrict__ topk_id, const float* __restrict__ topk_w,
                         const int* __restrict__ offs, int* __restrict__ cursor,
                         int* __restrict__ slot_tok, float* __restrict__ slot_w) {
  int i = blockIdx.x * blockDim.x + threadIdx.x;
  if (i >= T_TOK * TOPK) return;
  int e = topk_id[i];
  int pos = offs[e] + atomicAdd(&cursor[e], 1);
  slot_tok[pos] = i >> 2;
  slot_w[pos] = topk_w[i];
}

// ---------------- K4: GEMM1  act = silu(x@w1g^T) * (x@w1u^T)  ----------------
// PRE=true: operands pre-converted to bf16 (xb/w1b) -> staging is a single
// 16B bf16x8 load per tile row (no in-loop cvt). PRE=false: round-9 f32 path.
template<bool PRE>
__global__ __launch_bounds__(256) void k_gemm1(
    const float* __restrict__ x, const float* __restrict__ w1,
    const ushort_t* __restrict__ xb, const ushort_t* __restrict__ w1b,
    const int* __restrict__ slot_tok, const int* __restrict__ offs,
    const int* __restrict__ cnt, __hip_bfloat16* __restrict__ act) {
  int e = blockIdx.z;
  int m0 = blockIdx.y * BM;
  int cntE = cnt[e];
  if (m0 >= cntE) return;
  int n0 = blockIdx.x * BN;
  int off = offs[e];

  __shared__ ushort_t sA[BM * LDSS];
  __shared__ ushort_t sG[BN * LDSS];
  __shared__ ushort_t sU[BN * LDSS];
  __shared__ int tok_s[BM];

  int tid = threadIdx.x;
  if (tid < BM) {
    int r = m0 + tid;
    tok_s[tid] = (r < cntE) ? slot_tok[off + r] : -1;
  }
  __syncthreads();

  int srow = tid >> 2;          // 0..63 staging row
  int scol = (tid & 3) * 8;     // 0,8,16,24 (elements)
  int mytok = tok_s[srow];

  const float* aptr = x + (size_t)(mytok < 0 ? 0 : mytok) * H_DIM + scol;
  const float* gptr = w1 + ((size_t)e * 2 * F_DIM + n0 + srow) * H_DIM + scol;
  const float* uptr = gptr + (size_t)F_DIM * H_DIM;
  const ushort_t* aptrb = xb + (size_t)(mytok < 0 ? 0 : mytok) * H_DIM + scol;
  const ushort_t* gptrb = w1b + ((size_t)e * 2 * F_DIM + n0 + srow) * H_DIM + scol;
  const ushort_t* uptrb = gptrb + (size_t)F_DIM * H_DIM;

  int wave = tid >> 6;
  int lane = tid & 63;
  int wr = wave >> 1, wc = wave & 1;
  int lrow = lane & 15;
  int kgrp = lane >> 4;

  f32x4 accg[2][2] = {};
  f32x4 accu[2][2] = {};

  int aoff0 = (wr * 32 + lrow) * LDSS + kgrp * 8;
  int boff0 = (wc * 32 + lrow) * LDSS + kgrp * 8;

  for (int k0 = 0; k0 < H_DIM; k0 += BK) {
    bf16x8 va = {0, 0, 0, 0, 0, 0, 0, 0}, vg, vu;
    if constexpr (PRE) {
      if (mytok >= 0) va = *(const bf16x8*)(aptrb + k0);
      vg = *(const bf16x8*)(gptrb + k0);
      vu = *(const bf16x8*)(uptrb + k0);
    } else {
      float4 va0 = make_float4(0, 0, 0, 0), va1 = va0;
      if (mytok >= 0) {
        va0 = *(const float4*)(aptr + k0);
        va1 = *(const float4*)(aptr + k0 + 4);
      }
      float4 vg0 = *(const float4*)(gptr + k0);
      float4 vg1 = *(const float4*)(gptr + k0 + 4);
      float4 vu0 = *(const float4*)(uptr + k0);
      float4 vu1 = *(const float4*)(uptr + k0 + 4);
      va[0] = (short)f2bf(va0.x); va[1] = (short)f2bf(va0.y); va[2] = (short)f2bf(va0.z); va[3] = (short)f2bf(va0.w);
      va[4] = (short)f2bf(va1.x); va[5] = (short)f2bf(va1.y); va[6] = (short)f2bf(va1.z); va[7] = (short)f2bf(va1.w);
      vg[0] = (short)f2bf(vg0.x); vg[1] = (short)f2bf(vg0.y); vg[2] = (short)f2bf(vg0.z); vg[3] = (short)f2bf(vg0.w);
      vg[4] = (short)f2bf(vg1.x); vg[5] = (short)f2bf(vg1.y); vg[6] = (short)f2bf(vg1.z); vg[7] = (short)f2bf(vg1.w);
      vu[0] = (short)f2bf(vu0.x); vu[1] = (short)f2bf(vu0.y); vu[2] = (short)f2bf(vu0.z); vu[3] = (short)f2bf(vu0.w);
      vu[4] = (short)f2bf(vu1.x); vu[5] = (short)f2bf(vu1.y); vu[6] = (short)f2bf(vu1.z); vu[7] = (short)f2bf(vu1.w);
    }

    __syncthreads();  // previous iter's LDS reads done before overwrite
    *(bf16x8*)&sA[srow * LDSS + scol] = va;
    *(bf16x8*)&sG[srow * LDSS + scol] = vg;
    *(bf16x8*)&sU[srow * LDSS + scol] = vu;
    __syncthreads();

    bf16x8 af[2], gf[2], uf[2];
    af[0] = *(const bf16x8*)&sA[aoff0];
    af[1] = *(const bf16x8*)&sA[aoff0 + 16 * LDSS];
    gf[0] = *(const bf16x8*)&sG[boff0];
    gf[1] = *(const bf16x8*)&sG[boff0 + 16 * LDSS];
    uf[0] = *(const bf16x8*)&sU[boff0];
    uf[1] = *(const bf16x8*)&sU[boff0 + 16 * LDSS];
#pragma unroll
    for (int i = 0; i < 2; ++i)
#pragma unroll
      for (int j = 0; j < 2; ++j) {
        accg[i][j] = __builtin_amdgcn_mfma_f32_16x16x32_bf16(af[i], gf[j], accg[i][j], 0, 0, 0);
        accu[i][j] = __builtin_amdgcn_mfma_f32_16x16x32_bf16(af[i], uf[j], accu[i][j], 0, 0, 0);
      }
  }

  // epilogue: silu(g)*u -> act (bf16). C layout: col=lane&15, row=(lane>>4)*4+reg
#pragma unroll
  for (int i = 0; i < 2; ++i) {
#pragma unroll
    for (int r = 0; r < 4; ++r) {
      int row = wr * 32 + i * 16 + kgrp * 4 + r;
      if (m0 + row < cntE) {
        size_t gslot = (size_t)(off + m0 + row);
        __hip_bfloat16* ap = act + gslot * F_DIM + n0 + wc * 32 + lrow;
#pragma unroll
        for (int j = 0; j < 2; ++j) {
          float g = accg[i][j][r];
          float u = accu[i][j][r];
          float a = (g / (1.f + __expf(-g))) * u;
          ap[j * 16] = __float2bfloat16(a);
        }
      }
    }
  }
}

// ---------------- K5: GEMM2  out[t] += w_slot * (act @ w2^T) ----------------
template<bool PRE>
__global__ __launch_bounds__(256) void k_gemm2(
    const __hip_bfloat16* __restrict__ act, const float* __restrict__ w2,
    const ushort_t* __restrict__ w2b,
    const int* __restrict__ slot_tok, const float* __restrict__ slot_w,
    const int* __restrict__ offs, const int* __restrict__ cnt,
    float* __restrict__ out) {
  int e = blockIdx.z;
  int m0 = blockIdx.y * BM;
  int cntE = cnt[e];
  if (m0 >= cntE) return;
  int n0 = blockIdx.x * BN;
  int off = offs[e];

  __shared__ ushort_t sA[BM * LDSS];
  __shared__ ushort_t sB[BN * LDSS];
  __shared__ int tok_s[BM];
  __shared__ float w_s[BM];

  int tid = threadIdx.x;
  if (tid < BM) {
    int r = m0 + tid;
    tok_s[tid] = (r < cntE) ? slot_tok[off + r] : 0;
    w_s[tid] = (r < cntE) ? slot_w[off + r] : 0.f;
  }
  __syncthreads();

  int srow = tid >> 2;
  int scol = (tid & 3) * 8;
  bool arow_ok = (m0 + srow) < cntE;
  const ushort_t* aptr = (const ushort_t*)act + (size_t)(off + m0 + (arow_ok ? srow : 0)) * F_DIM + scol;
  const float* bptr = w2 + ((size_t)e * H_DIM + n0 + srow) * F_DIM + scol;
  const ushort_t* bptrb = w2b + ((size_t)e * H_DIM + n0 + srow) * F_DIM + scol;

  int wave = tid >> 6;
  int lane = tid & 63;
  int wr = wave >> 1, wc = wave & 1;
  int lrow = lane & 15;
  int kgrp = lane >> 4;

  f32x4 acc[2][2] = {};

  int aoff0 = (wr * 32 + lrow) * LDSS + kgrp * 8;
  int boff0 = (wc * 32 + lrow) * LDSS + kgrp * 8;

  for (int k0 = 0; k0 < F_DIM; k0 += BK) {
    bf16x8 av = {0, 0, 0, 0, 0, 0, 0, 0}, vb;
    if (arow_ok) av = *(const bf16x8*)(aptr + k0);
    if constexpr (PRE) {
      vb = *(const bf16x8*)(bptrb + k0);
    } else {
      float4 vb0 = *(const float4*)(bptr + k0);
      float4 vb1 = *(const float4*)(bptr + k0 + 4);
      vb[0] = (short)f2bf(vb0.x); vb[1] = (short)f2bf(vb0.y); vb[2] = (short)f2bf(vb0.z); vb[3] = (short)f2bf(vb0.w);
      vb[4] = (short)f2bf(vb1.x); vb[5] = (short)f2bf(vb1.y); vb[6] = (short)f2bf(vb1.z); vb[7] = (short)f2bf(vb1.w);
    }

    __syncthreads();
    *(bf16x8*)&sA[srow * LDSS + scol] = av;
    *(bf16x8*)&sB[srow * LDSS + scol] = vb;
    __syncthreads();

    bf16x8 af[2], bf[2];
    af[0] = *(const bf16x8*)&sA[aoff0];
    af[1] = *(const bf16x8*)&sA[aoff0 + 16 * LDSS];
    bf[0] = *(const bf16x8*)&sB[boff0];
    bf[1] = *(const bf16x8*)&sB[boff0 + 16 * LDSS];
#pragma unroll
    for (int i = 0; i < 2; ++i)
#pragma unroll
      for (int j = 0; j < 2; ++j)
        acc[i][j] = __builtin_amdgcn_mfma_f32_16x16x32_bf16(af[i], bf[j], acc[i][j], 0, 0, 0);
  }

#pragma unroll
  for (int i = 0; i < 2; ++i) {
#pragma unroll
    for (int r = 0; r < 4; ++r) {
      int row = wr * 32 + i * 16 + kgrp * 4 + r;
      if (m0 + row < cntE) {
        int tok = tok_s[row];
        float wgt = w_s[row];
        float* op = out + (size_t)tok * H_DIM + n0 + wc * 32 + lrow;
#pragma unroll
        for (int j = 0; j < 2; ++j)
          atomicAdd(op + j * 16, acc[i][j][r] * wgt);
      }
    }
  }
}

// ---------------- launch ----------------
extern "C" void kernel_launch(void* const* d_in, const int* in_sizes, int n_in,
                              void* d_out, int out_size, void* d_ws, size_t ws_size,
                              hipStream_t stream) {
  const float* x  = (const float*)d_in[0];
  const float* gw = (const float*)d_in[1];
  const float* w1 = (const float*)d_in[2];
  const float* w2 = (const float*)d_in[3];
  float* out = (float*)d_out;

  char* base = (char*)d_ws;
  int* cnt      = (int*)(base);
  int* cursor   = (int*)(base + 64);
  int* offs     = (int*)(base + 128);
  int* topk_id  = (int*)(base + 256);
  float* topk_w = (float*)(base + 256 + 16384);
  int* slot_tok = (int*)(base + 256 + 32768);
  float* slot_w = (float*)(base + 256 + 49152);
  float* logits = (float*)(base + 256 + 65536);                 // 1024*16 f32 = 64KB
  __hip_bfloat16* act = (__hip_bfloat16*)(base + 256 + 131072); // 4096*768 bf16 = 6.29MB

  // pre-converted bf16 operands (only if workspace is large enough)
  const size_t XB_OFF  = (size_t)8 << 20;                  // xb at 8 MB (act ends ~6.4 MB)
  const size_t W1B_OFF = XB_OFF + ((size_t)2 << 20);       // w1b at 10 MB
  const size_t W2B_OFF = W1B_OFF + (size_t)E_NUM * 2 * F_DIM * H_DIM * 2;
  const size_t NEED    = W2B_OFF + (size_t)E_NUM * H_DIM * F_DIM * 2;
  bool pre = ws_size >= NEED;
  ushort_t* xb  = (ushort_t*)(base + XB_OFF);
  ushort_t* w1b = (ushort_t*)(base + W1B_OFF);
  ushort_t* w2b = (ushort_t*)(base + W2B_OFF);

  k_zero<<<512, 256, 0, stream>>>(out, T_TOK * H_DIM, cnt);
  if (pre) {
    k_cvt<<<2048, 256, 0, stream>>>(w1, w1b, E_NUM * 2 * F_DIM * H_DIM / 8);
    k_cvt<<<1024, 256, 0, stream>>>(w2, w2b, E_NUM * H_DIM * F_DIM / 8);
    k_cvt<<<256, 256, 0, stream>>>(x, xb, T_TOK * H_DIM / 8);
  }
  k_logits<<<T_TOK * E_NUM / 4, 256, 0, stream>>>(x, gw, logits);
  k_topk<<<(T_TOK + 255) / 256, 256, 0, stream>>>(logits, cnt, topk_id, topk_w);
  k_scan<<<1, 64, 0, stream>>>(cnt, offs, cursor);
  k_assign<<<(T_TOK * TOPK + 255) / 256, 256, 0, stream>>>(topk_id, topk_w, offs, cursor, slot_tok, slot_w);
  if (pre) {
    k_gemm1<true><<<dim3(F_DIM / BN, T_TOK / BM, E_NUM), 256, 0, stream>>>(
        x, w1, xb, w1b, slot_tok, offs, cnt, act);
    k_gemm2<true><<<dim3(H_DIM / BN, T_TOK / BM, E_NUM), 256, 0, stream>>>(
        act, w2, w2b, slot_tok, slot_w, offs, cnt, out);
  } else {
    k_gemm1<false><<<dim3(F_DIM / BN, T_TOK / BM, E_NUM), 256, 0, stream>>>(
        x, w1, xb, w1b, slot_tok, offs, cnt, act);
    k_gemm2<false><<<dim3(H_DIM / BN, T_TOK / BM, E_NUM), 256, 0, stream>>>(
        act, w2, w2b, slot_tok, slot_w, offs, cnt, out);
  }
}

// Round 14
// 314.318 us; speedup vs baseline: 1.3301x; 1.0060x over previous
//
#include <hip/hip_runtime.h>
#include <hip/hip_bf16.h>

#define T_TOK 1024
#define H_DIM 1024
#define F_DIM 768
#define E_NUM 16
#define TOPK  4

#define BM 64
#define BN 64
#define BK 32
#define LDSS 40   // LDS row stride in ushorts (80B) -> <=2-way bank conflict (free)

typedef __attribute__((ext_vector_type(8))) short bf16x8;
typedef __attribute__((ext_vector_type(4))) float f32x4;
typedef unsigned short ushort_t;

__device__ __forceinline__ ushort_t f2bf(float f) {
  __hip_bfloat16 h = __float2bfloat16(f);
  return *reinterpret_cast<ushort_t*>(&h);
}

// ---------------- K0: zero output + counters (FALLBACK path only) ----------
__global__ void k_zero(float* __restrict__ out, int n, int* __restrict__ cnt) {
  int i = blockIdx.x * blockDim.x + threadIdx.x;
  if (i < E_NUM) cnt[i] = 0;
  for (; i < n; i += gridDim.x * blockDim.x) out[i] = 0.f;
}

// ---------------- K0b: fused f32 -> bf16 convert of w1, w2, x --------------
__global__ __launch_bounds__(256) void k_cvt_all(
    const float* __restrict__ w1, ushort_t* __restrict__ w1b,
    const float* __restrict__ w2, ushort_t* __restrict__ w2b,
    const float* __restrict__ x,  ushort_t* __restrict__ xb) {
  const int N1 = E_NUM * 2 * F_DIM * H_DIM / 8;
  const int N2 = E_NUM * H_DIM * F_DIM / 8;
  const int N3 = T_TOK * H_DIM / 8;
  int i = blockIdx.x * blockDim.x + threadIdx.x;
  int stride = gridDim.x * blockDim.x;
  for (; i < N1 + N2 + N3; i += stride) {
    const float* s; ushort_t* d; int j;
    if (i < N1)            { s = w1; d = w1b; j = i; }
    else if (i < N1 + N2)  { s = w2; d = w2b; j = i - N1; }
    else                   { s = x;  d = xb;  j = i - N1 - N2; }
    const float4* sp = (const float4*)(s + (size_t)j * 8);
    float4 a = sp[0], b = sp[1];
    bf16x8 v;
    v[0] = (short)f2bf(a.x); v[1] = (short)f2bf(a.y); v[2] = (short)f2bf(a.z); v[3] = (short)f2bf(a.w);
    v[4] = (short)f2bf(b.x); v[5] = (short)f2bf(b.y); v[6] = (short)f2bf(b.z); v[7] = (short)f2bf(b.w);
    *(bf16x8*)(d + (size_t)j * 8) = v;
  }
}

// ---------------- K1a: logits — one wave per (token, expert) ----------------
// block 0 also zeroes cnt (runs before k_topk's atomics, stream-ordered).
__global__ __launch_bounds__(256) void k_logits(
    const float* __restrict__ x, const float* __restrict__ gw,
    float* __restrict__ logits, int* __restrict__ cnt) {
  if (blockIdx.x == 0 && threadIdx.x < E_NUM) cnt[threadIdx.x] = 0;
  int wid = blockIdx.x * 4 + (threadIdx.x >> 6);   // 0..16383
  int lane = threadIdx.x & 63;
  int t = wid >> 4;
  int e = wid & (E_NUM - 1);
  const float* xr = x + (size_t)t * H_DIM;
  const float* g  = gw + (size_t)e * H_DIM;
  float s = 0.f;
#pragma unroll
  for (int j = 0; j < 16; ++j) s += xr[lane + j * 64] * g[lane + j * 64];
#pragma unroll
  for (int off = 32; off >= 1; off >>= 1) s += __shfl_xor(s, off);
  if (lane == 0) logits[t * E_NUM + e] = s;
}

// ---------------- K1b: top-4 + softmax — one thread per token ----------------
__global__ __launch_bounds__(256) void k_topk(
    const float* __restrict__ logits, int* __restrict__ cnt,
    int* __restrict__ topk_id, float* __restrict__ topk_w) {
  int t = blockIdx.x * blockDim.x + threadIdx.x;
  if (t >= T_TOK) return;

  float lg[E_NUM];
#pragma unroll
  for (int e = 0; e < E_NUM; ++e) lg[e] = logits[t * E_NUM + e];

  int ids[TOPK];
  float vals[TOPK];
  unsigned used = 0;
#pragma unroll
  for (int k = 0; k < TOPK; ++k) {
    float best = -3.0e38f;
    int bi = 0;
#pragma unroll
    for (int e = 0; e < E_NUM; ++e) {
      bool skip = (used >> e) & 1;
      if (!skip && lg[e] > best) { best = lg[e]; bi = e; }
    }
    used |= 1u << bi;
    ids[k] = bi;
    vals[k] = best;
  }
  float m = vals[0];
  float w[TOPK];
  float sum = 0.f;
#pragma unroll
  for (int k = 0; k < TOPK; ++k) { w[k] = __expf(vals[k] - m); sum += w[k]; }
  float inv = 1.f / sum;

#pragma unroll
  for (int k = 0; k < TOPK; ++k) {
    topk_id[t * TOPK + k] = ids[k];
    topk_w[t * TOPK + k] = w[k] * inv;
    atomicAdd(&cnt[ids[k]], 1);
  }
}

// ---------------- K2: exclusive scan of counts ----------------
__global__ void k_scan(const int* __restrict__ cnt, int* __restrict__ offs,
                       int* __restrict__ cursor) {
  if (threadIdx.x == 0) {
    int r = 0;
    for (int e = 0; e < E_NUM; ++e) { offs[e] = r; r += cnt[e]; cursor[e] = 0; }
  }
}

// ---------------- K3: fill per-expert slot lists (+ inverse map) ------------
__global__ void k_assign(const int* __restrict__ topk_id, const float* __restrict__ topk_w,
                         const int* __restrict__ offs, int* __restrict__ cursor,
                         int* __restrict__ slot_tok, float* __restrict__ slot_w,
                         int* __restrict__ slot_of) {
  int i = blockIdx.x * blockDim.x + threadIdx.x;
  if (i >= T_TOK * TOPK) return;
  int e = topk_id[i];
  int pos = offs[e] + atomicAdd(&cursor[e], 1);
  slot_tok[pos] = i >> 2;
  slot_w[pos] = topk_w[i];
  slot_of[i] = pos;
}

// ---------------- K4: GEMM1  act = silu(x@w1g^T) * (x@w1u^T)  ----------------
template<bool PRE>
__global__ __launch_bounds__(256) void k_gemm1(
    const float* __restrict__ x, const float* __restrict__ w1,
    const ushort_t* __restrict__ xb, const ushort_t* __restrict__ w1b,
    const int* __restrict__ slot_tok, const int* __restrict__ offs,
    const int* __restrict__ cnt, __hip_bfloat16* __restrict__ act) {
  int e = blockIdx.z;
  int m0 = blockIdx.y * BM;
  int cntE = cnt[e];
  if (m0 >= cntE) return;
  int n0 = blockIdx.x * BN;
  int off = offs[e];

  __shared__ ushort_t sA[BM * LDSS];
  __shared__ ushort_t sG[BN * LDSS];
  __shared__ ushort_t sU[BN * LDSS];
  __shared__ int tok_s[BM];

  int tid = threadIdx.x;
  if (tid < BM) {
    int r = m0 + tid;
    tok_s[tid] = (r < cntE) ? slot_tok[off + r] : -1;
  }
  __syncthreads();

  int srow = tid >> 2;          // 0..63 staging row
  int scol = (tid & 3) * 8;     // 0,8,16,24 (elements)
  int mytok = tok_s[srow];

  const float* aptr = x + (size_t)(mytok < 0 ? 0 : mytok) * H_DIM + scol;
  const float* gptr = w1 + ((size_t)e * 2 * F_DIM + n0 + srow) * H_DIM + scol;
  const float* uptr = gptr + (size_t)F_DIM * H_DIM;
  const ushort_t* aptrb = xb + (size_t)(mytok < 0 ? 0 : mytok) * H_DIM + scol;
  const ushort_t* gptrb = w1b + ((size_t)e * 2 * F_DIM + n0 + srow) * H_DIM + scol;
  const ushort_t* uptrb = gptrb + (size_t)F_DIM * H_DIM;

  int wave = tid >> 6;
  int lane = tid & 63;
  int wr = wave >> 1, wc = wave & 1;
  int lrow = lane & 15;
  int kgrp = lane >> 4;

  f32x4 accg[2][2] = {};
  f32x4 accu[2][2] = {};

  int aoff0 = (wr * 32 + lrow) * LDSS + kgrp * 8;
  int boff0 = (wc * 32 + lrow) * LDSS + kgrp * 8;

  for (int k0 = 0; k0 < H_DIM; k0 += BK) {
    bf16x8 va = {0, 0, 0, 0, 0, 0, 0, 0}, vg, vu;
    if constexpr (PRE) {
      if (mytok >= 0) va = *(const bf16x8*)(aptrb + k0);
      vg = *(const bf16x8*)(gptrb + k0);
      vu = *(const bf16x8*)(uptrb + k0);
    } else {
      float4 va0 = make_float4(0, 0, 0, 0), va1 = va0;
      if (mytok >= 0) {
        va0 = *(const float4*)(aptr + k0);
        va1 = *(const float4*)(aptr + k0 + 4);
      }
      float4 vg0 = *(const float4*)(gptr + k0);
      float4 vg1 = *(const float4*)(gptr + k0 + 4);
      float4 vu0 = *(const float4*)(uptr + k0);
      float4 vu1 = *(const float4*)(uptr + k0 + 4);
      va[0] = (short)f2bf(va0.x); va[1] = (short)f2bf(va0.y); va[2] = (short)f2bf(va0.z); va[3] = (short)f2bf(va0.w);
      va[4] = (short)f2bf(va1.x); va[5] = (short)f2bf(va1.y); va[6] = (short)f2bf(va1.z); va[7] = (short)f2bf(va1.w);
      vg[0] = (short)f2bf(vg0.x); vg[1] = (short)f2bf(vg0.y); vg[2] = (short)f2bf(vg0.z); vg[3] = (short)f2bf(vg0.w);
      vg[4] = (short)f2bf(vg1.x); vg[5] = (short)f2bf(vg1.y); vg[6] = (short)f2bf(vg1.z); vg[7] = (short)f2bf(vg1.w);
      vu[0] = (short)f2bf(vu0.x); vu[1] = (short)f2bf(vu0.y); vu[2] = (short)f2bf(vu0.z); vu[3] = (short)f2bf(vu0.w);
      vu[4] = (short)f2bf(vu1.x); vu[5] = (short)f2bf(vu1.y); vu[6] = (short)f2bf(vu1.z); vu[7] = (short)f2bf(vu1.w);
    }

    __syncthreads();  // previous iter's LDS reads done before overwrite
    *(bf16x8*)&sA[srow * LDSS + scol] = va;
    *(bf16x8*)&sG[srow * LDSS + scol] = vg;
    *(bf16x8*)&sU[srow * LDSS + scol] = vu;
    __syncthreads();

    bf16x8 af[2], gf[2], uf[2];
    af[0] = *(const bf16x8*)&sA[aoff0];
    af[1] = *(const bf16x8*)&sA[aoff0 + 16 * LDSS];
    gf[0] = *(const bf16x8*)&sG[boff0];
    gf[1] = *(const bf16x8*)&sG[boff0 + 16 * LDSS];
    uf[0] = *(const bf16x8*)&sU[boff0];
    uf[1] = *(const bf16x8*)&sU[boff0 + 16 * LDSS];
#pragma unroll
    for (int i = 0; i < 2; ++i)
#pragma unroll
      for (int j = 0; j < 2; ++j) {
        accg[i][j] = __builtin_amdgcn_mfma_f32_16x16x32_bf16(af[i], gf[j], accg[i][j], 0, 0, 0);
        accu[i][j] = __builtin_amdgcn_mfma_f32_16x16x32_bf16(af[i], uf[j], accu[i][j], 0, 0, 0);
      }
  }

  // epilogue: silu(g)*u -> act (bf16). C layout: col=lane&15, row=(lane>>4)*4+reg
#pragma unroll
  for (int i = 0; i < 2; ++i) {
#pragma unroll
    for (int r = 0; r < 4; ++r) {
      int row = wr * 32 + i * 16 + kgrp * 4 + r;
      if (m0 + row < cntE) {
        size_t gslot = (size_t)(off + m0 + row);
        __hip_bfloat16* ap = act + gslot * F_DIM + n0 + wc * 32 + lrow;
#pragma unroll
        for (int j = 0; j < 2; ++j) {
          float g = accg[i][j][r];
          float u = accu[i][j][r];
          float a = (g / (1.f + __expf(-g))) * u;
          ap[j * 16] = __float2bfloat16(a);
        }
      }
    }
  }
}

// ---------------- K5a: GEMM2 -> per-slot buffer (no atomics) ----------------
__global__ __launch_bounds__(256) void k_gemm2eo(
    const __hip_bfloat16* __restrict__ act, const ushort_t* __restrict__ w2b,
    const float* __restrict__ slot_w,
    const int* __restrict__ offs, const int* __restrict__ cnt,
    float* __restrict__ eo) {
  int e = blockIdx.z;
  int m0 = blockIdx.y * BM;
  int cntE = cnt[e];
  if (m0 >= cntE) return;
  int n0 = blockIdx.x * BN;
  int off = offs[e];

  __shared__ ushort_t sA[BM * LDSS];
  __shared__ ushort_t sB[BN * LDSS];
  __shared__ float w_s[BM];

  int tid = threadIdx.x;
  if (tid < BM) {
    int r = m0 + tid;
    w_s[tid] = (r < cntE) ? slot_w[off + r] : 0.f;
  }
  __syncthreads();

  int srow = tid >> 2;
  int scol = (tid & 3) * 8;
  bool arow_ok = (m0 + srow) < cntE;
  const ushort_t* aptr = (const ushort_t*)act + (size_t)(off + m0 + (arow_ok ? srow : 0)) * F_DIM + scol;
  const ushort_t* bptrb = w2b + ((size_t)e * H_DIM + n0 + srow) * F_DIM + scol;

  int wave = tid >> 6;
  int lane = tid & 63;
  int wr = wave >> 1, wc = wave & 1;
  int lrow = lane & 15;
  int kgrp = lane >> 4;

  f32x4 acc[2][2] = {};

  int aoff0 = (wr * 32 + lrow) * LDSS + kgrp * 8;
  int boff0 = (wc * 32 + lrow) * LDSS + kgrp * 8;

  for (int k0 = 0; k0 < F_DIM; k0 += BK) {
    bf16x8 av = {0, 0, 0, 0, 0, 0, 0, 0};
    if (arow_ok) av = *(const bf16x8*)(aptr + k0);
    bf16x8 vb = *(const bf16x8*)(bptrb + k0);

    __syncthreads();
    *(bf16x8*)&sA[srow * LDSS + scol] = av;
    *(bf16x8*)&sB[srow * LDSS + scol] = vb;
    __syncthreads();

    bf16x8 af[2], bf[2];
    af[0] = *(const bf16x8*)&sA[aoff0];
    af[1] = *(const bf16x8*)&sA[aoff0 + 16 * LDSS];
    bf[0] = *(const bf16x8*)&sB[boff0];
    bf[1] = *(const bf16x8*)&sB[boff0 + 16 * LDSS];
#pragma unroll
    for (int i = 0; i < 2; ++i)
#pragma unroll
      for (int j = 0; j < 2; ++j)
        acc[i][j] = __builtin_amdgcn_mfma_f32_16x16x32_bf16(af[i], bf[j], acc[i][j], 0, 0, 0);
  }

#pragma unroll
  for (int i = 0; i < 2; ++i) {
#pragma unroll
    for (int r = 0; r < 4; ++r) {
      int row = wr * 32 + i * 16 + kgrp * 4 + r;
      if (m0 + row < cntE) {
        float wgt = w_s[row];
        float* op = eo + (size_t)(off + m0 + row) * H_DIM + n0 + wc * 32 + lrow;
#pragma unroll
        for (int j = 0; j < 2; ++j)
          op[j * 16] = acc[i][j][r] * wgt;
      }
    }
  }
}

// ---------------- K5b (FALLBACK): GEMM2 with atomic combine ----------------
__global__ __launch_bounds__(256) void k_gemm2_atomic(
    const __hip_bfloat16* __restrict__ act, const float* __restrict__ w2,
    const int* __restrict__ slot_tok, const float* __restrict__ slot_w,
    const int* __restrict__ offs, const int* __restrict__ cnt,
    float* __restrict__ out) {
  int e = blockIdx.z;
  int m0 = blockIdx.y * BM;
  int cntE = cnt[e];
  if (m0 >= cntE) return;
  int n0 = blockIdx.x * BN;
  int off = offs[e];

  __shared__ ushort_t sA[BM * LDSS];
  __shared__ ushort_t sB[BN * LDSS];
  __shared__ int tok_s[BM];
  __shared__ float w_s[BM];

  int tid = threadIdx.x;
  if (tid < BM) {
    int r = m0 + tid;
    tok_s[tid] = (r < cntE) ? slot_tok[off + r] : 0;
    w_s[tid] = (r < cntE) ? slot_w[off + r] : 0.f;
  }
  __syncthreads();

  int srow = tid >> 2;
  int scol = (tid & 3) * 8;
  bool arow_ok = (m0 + srow) < cntE;
  const ushort_t* aptr = (const ushort_t*)act + (size_t)(off + m0 + (arow_ok ? srow : 0)) * F_DIM + scol;
  const float* bptr = w2 + ((size_t)e * H_DIM + n0 + srow) * F_DIM + scol;

  int wave = tid >> 6;
  int lane = tid & 63;
  int wr = wave >> 1, wc = wave & 1;
  int lrow = lane & 15;
  int kgrp = lane >> 4;

  f32x4 acc[2][2] = {};

  int aoff0 = (wr * 32 + lrow) * LDSS + kgrp * 8;
  int boff0 = (wc * 32 + lrow) * LDSS + kgrp * 8;

  for (int k0 = 0; k0 < F_DIM; k0 += BK) {
    bf16x8 av = {0, 0, 0, 0, 0, 0, 0, 0}, vb;
    if (arow_ok) av = *(const bf16x8*)(aptr + k0);
    float4 vb0 = *(const float4*)(bptr + k0);
    float4 vb1 = *(const float4*)(bptr + k0 + 4);
    vb[0] = (short)f2bf(vb0.x); vb[1] = (short)f2bf(vb0.y); vb[2] = (short)f2bf(vb0.z); vb[3] = (short)f2bf(vb0.w);
    vb[4] = (short)f2bf(vb1.x); vb[5] = (short)f2bf(vb1.y); vb[6] = (short)f2bf(vb1.z); vb[7] = (short)f2bf(vb1.w);

    __syncthreads();
    *(bf16x8*)&sA[srow * LDSS + scol] = av;
    *(bf16x8*)&sB[srow * LDSS + scol] = vb;
    __syncthreads();

    bf16x8 af[2], bf[2];
    af[0] = *(const bf16x8*)&sA[aoff0];
    af[1] = *(const bf16x8*)&sA[aoff0 + 16 * LDSS];
    bf[0] = *(const bf16x8*)&sB[boff0];
    bf[1] = *(const bf16x8*)&sB[boff0 + 16 * LDSS];
#pragma unroll
    for (int i = 0; i < 2; ++i)
#pragma unroll
      for (int j = 0; j < 2; ++j)
        acc[i][j] = __builtin_amdgcn_mfma_f32_16x16x32_bf16(af[i], bf[j], acc[i][j], 0, 0, 0);
  }

#pragma unroll
  for (int i = 0; i < 2; ++i) {
#pragma unroll
    for (int r = 0; r < 4; ++r) {
      int row = wr * 32 + i * 16 + kgrp * 4 + r;
      if (m0 + row < cntE) {
        int tok = tok_s[row];
        float wgt = w_s[row];
        float* op = out + (size_t)tok * H_DIM + n0 + wc * 32 + lrow;
#pragma unroll
        for (int j = 0; j < 2; ++j)
          atomicAdd(op + j * 16, acc[i][j][r] * wgt);
      }
    }
  }
}

// ---------------- K6: combine 4 slots per token (no atomics) ----------------
__global__ __launch_bounds__(256) void k_combine(
    const float* __restrict__ eo, const int* __restrict__ slot_of,
    float* __restrict__ out) {
  int t = blockIdx.x;
  int h = threadIdx.x * 4;
  int s0 = slot_of[t * TOPK + 0];
  int s1 = slot_of[t * TOPK + 1];
  int s2 = slot_of[t * TOPK + 2];
  int s3 = slot_of[t * TOPK + 3];
  float4 a = *(const float4*)(eo + (size_t)s0 * H_DIM + h);
  float4 b = *(const float4*)(eo + (size_t)s1 * H_DIM + h);
  float4 c = *(const float4*)(eo + (size_t)s2 * H_DIM + h);
  float4 d = *(const float4*)(eo + (size_t)s3 * H_DIM + h);
  float4 r;
  r.x = ((a.x + b.x) + c.x) + d.x;
  r.y = ((a.y + b.y) + c.y) + d.y;
  r.z = ((a.z + b.z) + c.z) + d.z;
  r.w = ((a.w + b.w) + c.w) + d.w;
  *(float4*)(out + (size_t)t * H_DIM + h) = r;
}

// ---------------- launch ----------------
extern "C" void kernel_launch(void* const* d_in, const int* in_sizes, int n_in,
                              void* d_out, int out_size, void* d_ws, size_t ws_size,
                              hipStream_t stream) {
  const float* x  = (const float*)d_in[0];
  const float* gw = (const float*)d_in[1];
  const float* w1 = (const float*)d_in[2];
  const float* w2 = (const float*)d_in[3];
  float* out = (float*)d_out;

  char* base = (char*)d_ws;
  int* cnt      = (int*)(base);
  int* cursor   = (int*)(base + 64);
  int* offs     = (int*)(base + 128);
  int* topk_id  = (int*)(base + 256);
  float* topk_w = (float*)(base + 256 + 16384);
  int* slot_tok = (int*)(base + 256 + 32768);
  float* slot_w = (float*)(base + 256 + 49152);
  float* logits = (float*)(base + 256 + 65536);                 // 64 KB
  __hip_bfloat16* act = (__hip_bfloat16*)(base + 256 + 131072); // 6.29 MB, ends ~6.42 MB
  int* slot_of  = (int*)(base + ((size_t)7 << 20));             // 16 KB at 7 MB

  const size_t XB_OFF  = (size_t)8 << 20;                       // 2 MB @ 8 MB
  const size_t W1B_OFF = XB_OFF + ((size_t)2 << 20);            // 50.33 MB @ 10 MB
  const size_t W2B_OFF = W1B_OFF + (size_t)E_NUM * 2 * F_DIM * H_DIM * 2;
  const size_t EO_OFF  = (size_t)86 << 20;                      // 16.78 MB @ 86 MB
  const size_t NEED    = EO_OFF + (size_t)T_TOK * TOPK * H_DIM * 4;
  bool pre = ws_size >= NEED;
  ushort_t* xb  = (ushort_t*)(base + XB_OFF);
  ushort_t* w1b = (ushort_t*)(base + W1B_OFF);
  ushort_t* w2b = (ushort_t*)(base + W2B_OFF);
  float* eo     = (float*)(base + EO_OFF);

  if (pre) {
    // 8-kernel path: no output atomics, fused cvt, no zero kernel
    k_cvt_all<<<2048, 256, 0, stream>>>(w1, w1b, w2, w2b, x, xb);
    k_logits<<<T_TOK * E_NUM / 4, 256, 0, stream>>>(x, gw, logits, cnt);
    k_topk<<<(T_TOK + 255) / 256, 256, 0, stream>>>(logits, cnt, topk_id, topk_w);
    k_scan<<<1, 64, 0, stream>>>(cnt, offs, cursor);
    k_assign<<<(T_TOK * TOPK + 255) / 256, 256, 0, stream>>>(
        topk_id, topk_w, offs, cursor, slot_tok, slot_w, slot_of);
    k_gemm1<true><<<dim3(F_DIM / BN, T_TOK / BM, E_NUM), 256, 0, stream>>>(
        x, w1, xb, w1b, slot_tok, offs, cnt, act);
    k_gemm2eo<<<dim3(H_DIM / BN, T_TOK / BM, E_NUM), 256, 0, stream>>>(
        act, w2b, slot_w, offs, cnt, eo);
    k_combine<<<T_TOK, 256, 0, stream>>>(eo, slot_of, out);
  } else {
    // fallback: round-13 f32 path with atomic combine
    k_zero<<<512, 256, 0, stream>>>(out, T_TOK * H_DIM, cnt);
    k_logits<<<T_TOK * E_NUM / 4, 256, 0, stream>>>(x, gw, logits, cnt);
    k_topk<<<(T_TOK + 255) / 256, 256, 0, stream>>>(logits, cnt, topk_id, topk_w);
    k_scan<<<1, 64, 0, stream>>>(cnt, offs, cursor);
    k_assign<<<(T_TOK * TOPK + 255) / 256, 256, 0, stream>>>(
        topk_id, topk_w, offs, cursor, slot_tok, slot_w, slot_of);
    k_gemm1<false><<<dim3(F_DIM / BN, T_TOK / BM, E_NUM), 256, 0, stream>>>(
        x, w1, xb, w1b, slot_tok, offs, cnt, act);
    k_gemm2_atomic<<<dim3(H_DIM / BN, T_TOK / BM, E_NUM), 256, 0, stream>>>(
        act, w2, slot_tok, slot_w, offs, cnt, out);
  }
}